// Round 16
// baseline (286.763 us; speedup 1.0000x reference)
//
#include <hip/hip_runtime.h>
#include <hip/hip_fp16.h>

#define N_NODES 100000
#define N_EDGES 1600000
#define IN_F 128
#define H_F 64

#define NCHUNK 64
#define CHUNK_E (N_EDGES / NCHUNK)      // 25000
#define NW (N_NODES / 4)                // 25000 u32 words per u8-packed table row

// histogram slicing: 4x u8 packed per u32 -> 50000 nodes in 50KB LDS
#define NSLICE_H 2
#define SLICE_H (N_NODES / NSLICE_H)    // 50000
// scatter slicing: u16 packed LOCAL counters -> 25000 nodes in 50KB LDS
#define NSLICE_S 4
#define SLICE_S (N_NODES / NSLICE_S)    // 25000

// ---------------- LDS histogram, u8 x4 packed; y=0 -> dst, y=1 -> src ----------------
__global__ __launch_bounds__(256) void hist_u8_kernel(
        const int* __restrict__ dst, const int* __restrict__ src,
        unsigned* __restrict__ pdst, unsigned* __restrict__ psrc) {
    __shared__ unsigned hist[SLICE_H / 4];   // 12500 words = 50 KB
    const int* idx = blockIdx.y ? src : dst;
    unsigned* partial = blockIdx.y ? psrc : pdst;
    int slice = blockIdx.x & (NSLICE_H - 1);
    int chunk = blockIdx.x >> 1;
    int lo = slice * SLICE_H;
    for (int t = threadIdx.x; t < SLICE_H / 4; t += 256) hist[t] = 0;
    __syncthreads();
    int e0 = chunk * CHUNK_E;
    for (int e = e0 + threadIdx.x; e < e0 + CHUNK_E; e += 256) {
        int d = idx[e] - lo;
        if ((unsigned)d < (unsigned)SLICE_H)
            atomicAdd(&hist[d >> 2], 1u << ((d & 3) << 3));
    }
    __syncthreads();
    unsigned* dstp = partial + (size_t)chunk * NW + (lo >> 2);
    for (int t = threadIdx.x; t < SLICE_H / 4; t += 256) dstp[t] = hist[t];
}

// ---------------- reduce u8 partials -> norms + block-level scan of deg_dst ----------------
__global__ void reduce_norm_scan_kernel(const unsigned* __restrict__ psrc,
                                        const unsigned* __restrict__ pdst,
                                        float* __restrict__ out_norm, float* __restrict__ in_norm,
                                        int* __restrict__ row_off, int* __restrict__ bsums, int N) {
    __shared__ int temp[256];
    int tid = threadIdx.x;
    int i = blockIdx.x * 256 + tid;
    int ds = 0, dd = 0;
    if (i < N) {
        int w = i >> 2, sh = (i & 3) << 3;
#pragma unroll
        for (int c = 0; c < NCHUNK; c++) {
            ds += (psrc[(size_t)c * NW + w] >> sh) & 0xFF;
            dd += (pdst[(size_t)c * NW + w] >> sh) & 0xFF;
        }
        out_norm[i] = rsqrtf((float)max(ds, 1));
        in_norm[i]  = rsqrtf((float)max(dd, 1));
    }
    temp[tid] = dd;
    __syncthreads();
    for (int off = 1; off < 256; off <<= 1) {
        int t = (tid >= off) ? temp[tid - off] : 0;
        __syncthreads();
        temp[tid] += t;
        __syncthreads();
    }
    int excl = (tid > 0) ? temp[tid - 1] : 0;
    if (i < N) row_off[i] = excl;
    if (tid == 255) bsums[blockIdx.x] = temp[255];
}

__global__ void scan_sums_kernel(int* __restrict__ bsums, int B) {
    __shared__ int temp[512];
    int tid = threadIdx.x;
    int v = (tid < B) ? bsums[tid] : 0;
    temp[tid] = v;
    __syncthreads();
    for (int off = 1; off < 512; off <<= 1) {
        int t = (tid >= off) ? temp[tid - off] : 0;
        __syncthreads();
        temp[tid] += t;
        __syncthreads();
    }
    int excl = (tid > 0) ? temp[tid - 1] : 0;
    if (tid < B) bsums[tid] = excl;
}

// ---------------- finalize row_off + transform pdst counts -> u8 rel-offsets IN PLACE ----
__global__ void scan_add_rel_kernel(int* __restrict__ row_off, const int* __restrict__ bsums,
                                    unsigned* __restrict__ pdst, int N, int E) {
    int i = blockIdx.x * 256 + threadIdx.x;
    if (i < N) row_off[i] += bsums[i >> 8];
    if (i == 0) row_off[N] = E;
    if (i < NW) {
        unsigned r0 = 0, r1 = 0, r2 = 0, r3 = 0;
#pragma unroll
        for (int c = 0; c < NCHUNK; c++) {
            unsigned wd = pdst[(size_t)c * NW + i];
            pdst[(size_t)c * NW + i] = r0 | (r1 << 8) | (r2 << 16) | (r3 << 24);
            r0 += wd & 0xFF; r1 += (wd >> 8) & 0xFF;
            r2 += (wd >> 16) & 0xFF; r3 += (wd >> 24) & 0xFF;
        }
    }
}

// ---------------- counting-sort scatter (standalone again; round-14 structure) ----------
// bid&7 = sel: slice = sel&3, chunk-half = sel>>2 -> each node's csr run written
// from <=2 XCDs under round-robin. u16 LDS local counters; final position =
// row_off[dst] + rel8[chunk][dst] + local. Zero global atomics.
__global__ __launch_bounds__(1024) void scatter_sort_kernel(
        const int* __restrict__ src, const int* __restrict__ dst,
        const unsigned* __restrict__ rel, const int* __restrict__ row_off,
        int* __restrict__ csr_src) {
    __shared__ unsigned cur[SLICE_S / 2];   // 12500 words = 50 KB
    int sel   = blockIdx.x & 7;
    int slice = sel & 3;
    int chalf = sel >> 2;
    int chunk = (blockIdx.x >> 3) + chalf * (NCHUNK / 2);
    int lo = slice * SLICE_S;
    for (int t = threadIdx.x; t < SLICE_S / 2; t += 1024) cur[t] = 0;
    __syncthreads();
    const unsigned* __restrict__ rp = rel + (size_t)chunk * NW;
    int e0 = chunk * CHUNK_E;
    for (int e = e0 + threadIdx.x; e < e0 + CHUNK_E; e += 1024) {
        int dd = dst[e];
        int d = dd - lo;
        if ((unsigned)d < (unsigned)SLICE_S) {
            unsigned sh = (d & 1) << 4;
            unsigned old = atomicAdd(&cur[d >> 1], 1u << sh);   // LDS atomic
            int local = (old >> sh) & 0xFFFF;
            int r8 = (rp[dd >> 2] >> ((dd & 3) << 3)) & 0xFF;
            csr_src[row_off[dd] + r8 + local] = src[e];
        }
    }
}

__device__ __forceinline__ unsigned pack_half2(float a, float b) {
    __half2 h = __halves2half2(__float2half_rn(a), __float2half_rn(b));
    return __builtin_bit_cast(unsigned, h);
}

// ---------------- quad-split GEMM with W staged in LDS ----------------
// Rounds 12-14: VALUBusy pinned ~25% because W (16-32KB) thrashes the ~16KB
// scalar K$ -> every k-group's s_load tuple misses to L2 (~250cy exposed).
// Fix: W in LDS (one-time block stage). All 64 lanes read the SAME LDS address
// -> hardware broadcast, zero bank conflicts; compiler pipelines ds_read_b128
// with lgkmcnt(N). Structure otherwise = proven round-13 quad-split: wave w
// owns column quarter h=w*16; all four 32B quarter-writes of a 128B output
// line come from the same block -> no cross-XCD partial-line RMW.
template <int K, typename TIN>
__global__ __launch_bounds__(256, 4) void gemm_lds_kernel(
        const TIN* __restrict__ in, const float* __restrict__ W,
        const float* __restrict__ scale, __half* __restrict__ out, int N) {
    __shared__ float Wl[K * 64];
    int tid = threadIdx.x;
#pragma unroll
    for (int i = tid; i < K * 16; i += 256)
        reinterpret_cast<float4*>(Wl)[i] = reinterpret_cast<const float4*>(W)[i];
    __syncthreads();

    int lane = tid & 63;
    int wave = tid >> 6;                    // 0..3 = column quarter
    int r = blockIdx.x * 64 + lane;
    const int h = wave * 16;
    if (r >= N) return;

    float acc[16];
#pragma unroll
    for (int j = 0; j < 16; j++) acc[j] = 0.f;

    const TIN* row = in + (size_t)r * K;
    for (int k = 0; k < K; k += 4) {
        float ax, ay, az, aw;
        if constexpr (sizeof(TIN) == 4) {
            float4 a = *reinterpret_cast<const float4*>(row + k);
            ax = a.x; ay = a.y; az = a.z; aw = a.w;
        } else {
            uint2 u = *reinterpret_cast<const uint2*>(row + k);
            __half2 h0 = __builtin_bit_cast(__half2, u.x);
            __half2 h1 = __builtin_bit_cast(__half2, u.y);
            ax = __low2float(h0); ay = __high2float(h0);
            az = __low2float(h1); aw = __high2float(h1);
        }
        const float* w0 = Wl + k * 64 + h;
#pragma unroll
        for (int j = 0; j < 16; j++) acc[j] = fmaf(ax, w0[j], acc[j]);
#pragma unroll
        for (int j = 0; j < 16; j++) acc[j] = fmaf(ay, w0[64 + j], acc[j]);
#pragma unroll
        for (int j = 0; j < 16; j++) acc[j] = fmaf(az, w0[128 + j], acc[j]);
#pragma unroll
        for (int j = 0; j < 16; j++) acc[j] = fmaf(aw, w0[192 + j], acc[j]);
    }

    float s = scale[r];
    uint4* o = reinterpret_cast<uint4*>(out + (size_t)r * 64 + h);
#pragma unroll
    for (int j = 0; j < 2; j++) {
        uint4 v;
        v.x = pack_half2(acc[8 * j + 0] * s, acc[8 * j + 1] * s);
        v.y = pack_half2(acc[8 * j + 2] * s, acc[8 * j + 3] * s);
        v.z = pack_half2(acc[8 * j + 4] * s, acc[8 * j + 5] * s);
        v.w = pack_half2(acc[8 * j + 6] * s, acc[8 * j + 7] * s);
        o[j] = v;
    }
}

// ---------------- CSR aggregation: fp16 gathers, scalar index loads, 16-deep batching ----------------
template <bool FUSE_HEAD>
__global__ __launch_bounds__(256) void agg_kernel(
        const __half* __restrict__ X, const int* __restrict__ row_off,
        const int* __restrict__ csr_src, const float* __restrict__ in_norm,
        const float* __restrict__ bias, const float* __restrict__ Wm,
        const float* __restrict__ bm, __half* __restrict__ outh,
        float* __restrict__ outf, int N) {
    int lane = threadIdx.x & 63;
    int wave = threadIdx.x >> 6;
    int v = blockIdx.x * (blockDim.x >> 6) + wave;
    if (v >= N) return;

    int start = __builtin_amdgcn_readfirstlane(row_off[v]);
    int end   = __builtin_amdgcn_readfirstlane(row_off[v + 1]);
    int deg = end - start;
    const int* __restrict__ idxp = csr_src + start;

    float acc0 = 0.f, acc1 = 0.f;
    int t = 0;
    for (; t + 16 <= deg; t += 16) {
        int s[16];
#pragma unroll
        for (int u = 0; u < 16; u++) s[u] = idxp[t + u];
        __half a[16];
#pragma unroll
        for (int u = 0; u < 16; u++) a[u] = X[(size_t)s[u] * 64 + lane];
        float f[16];
#pragma unroll
        for (int u = 0; u < 16; u++) f[u] = __half2float(a[u]);
        acc0 += (((f[0] + f[1]) + (f[2] + f[3])) + ((f[4] + f[5]) + (f[6] + f[7])));
        acc1 += (((f[8] + f[9]) + (f[10] + f[11])) + ((f[12] + f[13]) + (f[14] + f[15])));
    }
    for (; t + 8 <= deg; t += 8) {
        int s[8];
#pragma unroll
        for (int u = 0; u < 8; u++) s[u] = idxp[t + u];
        __half a[8];
#pragma unroll
        for (int u = 0; u < 8; u++) a[u] = X[(size_t)s[u] * 64 + lane];
        float f[8];
#pragma unroll
        for (int u = 0; u < 8; u++) f[u] = __half2float(a[u]);
        acc0 += (((f[0] + f[1]) + (f[2] + f[3])) + ((f[4] + f[5]) + (f[6] + f[7])));
    }
    for (; t < deg; t++) {
        int s = idxp[t];
        acc0 += __half2float(X[(size_t)s * 64 + lane]);
    }
    float acc = acc0 + acc1;

    float h = fmaf(acc, in_norm[v], bias[lane]);
    h = fmaxf(h, 0.f);

    if (!FUSE_HEAD) {
        outh[(size_t)v * 64 + lane] = __float2half_rn(h);
    } else {
        float p0 = h * Wm[lane * 2 + 0];
        float p1 = h * Wm[lane * 2 + 1];
#pragma unroll
        for (int off = 32; off > 0; off >>= 1) {
            p0 += __shfl_xor(p0, off);
            p1 += __shfl_xor(p1, off);
        }
        if (lane == 0) {
            outf[(size_t)v * 2 + 0] = p0 + bm[0];
            outf[(size_t)v * 2 + 1] = p1 + bm[1];
        }
    }
}

extern "C" void kernel_launch(void* const* d_in, const int* in_sizes, int n_in,
                              void* d_out, int out_size, void* d_ws, size_t ws_size,
                              hipStream_t stream) {
    const float* feature = (const float*)d_in[0];
    const float* W1 = (const float*)d_in[1];
    const float* b1 = (const float*)d_in[2];
    const float* W2 = (const float*)d_in[3];
    const float* b2 = (const float*)d_in[4];
    const float* Wm = (const float*)d_in[5];
    const float* bm = (const float*)d_in[6];
    const int* src = (const int*)d_in[7];
    const int* dst = (const int*)d_in[8];
    float* out = (float*)d_out;

    const int N = N_NODES, E = N_EDGES;

    char* p = (char*)d_ws;
    float* out_norm = (float*)p; p += (size_t)N * 4;
    float* in_norm = (float*)p;  p += (size_t)N * 4;
    int* row_off = (int*)p;      p += (size_t)(N + 1) * 4;
    int* bsums = (int*)p;        p += 512 * 4;
    int* csr_src = (int*)p;      p += (size_t)E * 4;        // 6.4 MB
    __half* X = (__half*)p;      p += (size_t)N * 64 * 2;   // 12.8 MB
    __half* H = (__half*)p;      p += (size_t)N * 64 * 2;   // 12.8 MB
    unsigned* pdst = (unsigned*)p; p += (size_t)NCHUNK * NW * 4;  // 6.4 MB
    unsigned* psrc = (unsigned*)p; p += (size_t)NCHUNK * NW * 4;  // 6.4 MB

    dim3 hgrid(NSLICE_H * NCHUNK, 2);   // 128 x 2
    hist_u8_kernel<<<hgrid, 256, 0, stream>>>(dst, src, pdst, psrc);

    int nScanBlocks = (N + 255) / 256;  // 391
    reduce_norm_scan_kernel<<<nScanBlocks, 256, 0, stream>>>(psrc, pdst, out_norm, in_norm,
                                                             row_off, bsums, N);
    scan_sums_kernel<<<1, 512, 0, stream>>>(bsums, nScanBlocks);
    scan_add_rel_kernel<<<nScanBlocks, 256, 0, stream>>>(row_off, bsums, pdst, N, E);

    scatter_sort_kernel<<<8 * (NCHUNK / 2), 1024, 0, stream>>>(src, dst, pdst, row_off,
                                                               csr_src);

    int ggrid = (N + 63) / 64;  // 1563 blocks
    // layer 1
    gemm_lds_kernel<128, float><<<ggrid, 256, 0, stream>>>(feature, W1, out_norm, X, N);
    agg_kernel<false><<<(N + 3) / 4, 256, 0, stream>>>(X, row_off, csr_src, in_norm, b1,
                                                       nullptr, nullptr, H, nullptr, N);
    // layer 2
    gemm_lds_kernel<64, __half><<<ggrid, 256, 0, stream>>>(H, W2, out_norm, X, N);
    // fused head
    agg_kernel<true><<<(N + 3) / 4, 256, 0, stream>>>(X, row_off, csr_src, in_norm, b2,
                                                      Wm, bm, nullptr, out, N);
}